// Round 1
// baseline (3123.011 us; speedup 1.0000x reference)
//
#include <hip/hip_runtime.h>
#include <math.h>

// Problem constants (fixed by reference):
// inputs (4,16,31,128,128) f32; W (48,16,3,3,3) f32; b (48) f32
// out (4,16,31,128,128) f32
#define NB 4
#define CH 16
#define TD 31
#define HH 128
#define WW 128
#define HW (HH * WW)

// Fully fused kernel: conv3d + activations + fo-pool recurrence.
// One thread owns a 4-wide w-quad of one (n,c,h) column, loops over t
// carrying the recurrence state in registers. c/n computed from blockIdx
// only -> weight indices are block-uniform -> scalar (s_load) weight reads.
__global__ __launch_bounds__(256) void qrnn_fused_kernel(
    const float* __restrict__ x,     // (4,16,31,128,128)
    const float* __restrict__ wt,    // (48,16,27)
    const float* __restrict__ bias,  // (48)
    float* __restrict__ out)         // (4,16,31,128,128)
{
    const int b   = blockIdx.x;          // 1024 blocks
    const int tid = threadIdx.x;         // 256 threads
    // Block-uniform (provable from blockIdx alone): c, n
    const int c = (b >> 4) & 15;
    const int n = b >> 8;
    // Per-thread: h (8 rows per block), w-quad (32 quads per row pair)
    const int h  = ((b & 15) << 3) + (tid >> 5);
    const int w0 = (tid & 31) << 2;

    const float bz = bias[c];
    const float bf = bias[c + 16];
    const float bo = bias[c + 32];

    const float* xin = x + (size_t)n * CH * TD * HW;
    float* po = out + ((size_t)(n * CH + c) * TD) * HW + (size_t)h * WW + w0;

    float cst[4] = {0.f, 0.f, 0.f, 0.f};

    for (int t = 0; t < TD; ++t) {
        float az[4] = {bz, bz, bz, bz};
        float af[4] = {bf, bf, bf, bf};
        float ao[4] = {bo, bo, bo, bo};

        for (int ic = 0; ic < CH; ++ic) {
            // wave-uniform weight pointers (z/f/o gates are oc = c, c+16, c+32)
            const float* wz = wt + ((size_t)(c      ) * CH + ic) * 27;
            const float* wf = wt + ((size_t)(c + 16) * CH + ic) * 27;
            const float* wo = wt + ((size_t)(c + 32) * CH + ic) * 27;
            const float* xi = xin + (size_t)ic * TD * HW;
            #pragma unroll
            for (int kd = 0; kd < 3; ++kd) {
                const int tt = t + kd - 1;
                if ((unsigned)tt >= (unsigned)TD) continue;   // SAME padding in t
                const float* xt = xi + (size_t)tt * HW;
                #pragma unroll
                for (int kh = 0; kh < 3; ++kh) {
                    const int hh = h + kh - 1;
                    if ((unsigned)hh >= (unsigned)HH) continue;  // SAME padding in h
                    const float* row = xt + (size_t)hh * WW;
                    // 6 input values cover kw in {-1,0,1} for 4 outputs
                    float xv[6];
                    xv[0] = (w0 > 0) ? row[w0 - 1] : 0.f;
                    const float4 v4 = *(const float4*)(row + w0);  // 16B-aligned
                    xv[1] = v4.x; xv[2] = v4.y; xv[3] = v4.z; xv[4] = v4.w;
                    xv[5] = (w0 + 4 < WW) ? row[w0 + 4] : 0.f;
                    const int kb = kd * 9 + kh * 3;
                    #pragma unroll
                    for (int kw = 0; kw < 3; ++kw) {
                        const float wzv = wz[kb + kw];
                        const float wfv = wf[kb + kw];
                        const float wov = wo[kb + kw];
                        #pragma unroll
                        for (int j = 0; j < 4; ++j) {
                            const float xx = xv[kw + j];
                            az[j] = fmaf(xx, wzv, az[j]);
                            af[j] = fmaf(xx, wfv, af[j]);
                            ao[j] = fmaf(xx, wov, ao[j]);
                        }
                    }
                }
            }
        }

        // activations + fo-pool step + store
        float4 hv;
        float* hp = (float*)&hv;
        #pragma unroll
        for (int j = 0; j < 4; ++j) {
            const float z = tanhf(az[j]);
            const float f = 1.f / (1.f + __expf(-af[j]));
            const float o = 1.f / (1.f + __expf(-ao[j]));
            cst[j] = f * cst[j] + (1.f - f) * z;
            hp[j] = o * cst[j];
        }
        *(float4*)po = hv;
        po += HW;
    }
}

extern "C" void kernel_launch(void* const* d_in, const int* in_sizes, int n_in,
                              void* d_out, int out_size, void* d_ws, size_t ws_size,
                              hipStream_t stream) {
    const float* x    = (const float*)d_in[0];  // (4,16,31,128,128)
    const float* wt   = (const float*)d_in[1];  // (48,16,3,3,3)
    const float* bias = (const float*)d_in[2];  // (48,)
    float* out = (float*)d_out;

    // grid: n(4) * c(16) * h-groups(16) = 1024 blocks of 256 threads
    qrnn_fused_kernel<<<dim3(1024), dim3(256), 0, stream>>>(x, wt, bias, out);
}

// Round 2
// 725.988 us; speedup vs baseline: 4.3017x; 4.3017x over previous
//
#include <hip/hip_runtime.h>

// QRNN3D fused: conv3d(16->48, 3x3x3, SAME) + gates + fo-pool, bf16 MFMA.
// x (4,16,31,128,128) f32 ; W (48,16,3,3,3) f32 ; b (48) f32 ; out (4,16,31,128,128) f32
//
// GEMM view: gates[48][px] = W[48][K=432] * im2col[K][px], K = tap*16+ic,
// tap = kd*9+kh*3+kw (27 real taps, padded to 28; pad tap has A==0).
// mfma_f32_16x16x32_bf16: A[m=lane&15][k=(lane>>4)*8+j], B[k][n=lane&15],
// C/D: col=lane&15, row=(lane>>4)*4+reg  (verified layouts per guide §3).
// Wave owns 32 pixels (2 C-tiles) x all 16 hidden ch; z/f/o accs are lane-
// aligned so the t-recurrence is pure per-lane register math.

typedef __attribute__((ext_vector_type(8))) short short8;   // bf16x8 frag
typedef __attribute__((ext_vector_type(4))) float float4v;  // f32x4 C/D frag

#define TD 31
#define HW (128 * 128)
#define LH 6                      // block h tile 4 + halo 2
#define LW 34                     // block w tile 32 + halo 2
#define PLANE8 (LH * LW * 2)      // short8 units per plane (2 chunks per cell)
#define PLANE_SHORTS (LH * LW * 16)

__device__ __forceinline__ short f2bf(float f) {
    unsigned u = __float_as_uint(f);
    u = (u + 0x7FFFu + ((u >> 16) & 1u)) >> 16;   // RNE
    return (short)u;
}

__global__ __launch_bounds__(256, 2) void qrnn_mfma_kernel(
    const float* __restrict__ x,
    const float* __restrict__ wt,
    const float* __restrict__ bias,
    float* __restrict__ out)
{
    __shared__ short8 xs8[3 * PLANE8];      // 19.6 KB: 3-plane ring, bf16
    short* xs = (short*)xs8;

    const int tid  = threadIdx.x;
    const int lane = tid & 63;
    const int wv   = tid >> 6;        // wave id = h row within block (0..3)
    const int q    = lane >> 4;       // quad
    const int px   = lane & 15;       // pixel-in-tile (w) ; also m for A gather
    const int b    = blockIdx.x;      // 512 blocks
    const int n    = b >> 7;
    const int hblk = (b >> 2) & 31;
    const int wblk = b & 3;
    const int h0   = hblk * 4;
    const int w0   = wblk * 32;

    const float* xin = x + (size_t)n * (16 * TD * HW);

    // ---- A fragments in registers: 3 gates x 14 K-steps (168 VGPRs, t-invariant)
    short8 afr[3][14];
#pragma unroll
    for (int g = 0; g < 3; ++g) {
#pragma unroll
        for (int s = 0; s < 14; ++s) {
            short8 a;
#pragma unroll
            for (int j = 0; j < 8; ++j) {
                int k   = s * 32 + q * 8 + j;
                int tap = k >> 4;
                int ic  = k & 15;
                float v = 0.f;
                if (tap < 27)          // tap 27 = K padding -> zero weight
                    v = wt[((size_t)((g * 16 + px) * 16 + ic)) * 27 + tap];
                a[j] = f2bf(v);
            }
            afr[g][s] = a;
        }
    }

    // bias for this lane's 4 C-rows per gate: channel = g*16 + q*4 + r
    float bval[3][4];
#pragma unroll
    for (int g = 0; g < 3; ++g)
#pragma unroll
        for (int r = 0; r < 4; ++r)
            bval[g][r] = bias[g * 16 + q * 4 + r];

    // output pointer: out[((n*16 + q*4 + r)*TD + t)*HW + (h0+wv)*128 + w0 + tile*16 + px]
    float* po = out + ((size_t)(n * 16 + q * 4) * TD) * HW
                    + (size_t)(h0 + wv) * 128 + w0 + px;

    float cst[2][4] = {{0.f,0.f,0.f,0.f},{0.f,0.f,0.f,0.f}};   // fo-pool state

    // ---- stage one t-plane into the ring (f32 -> bf16, ic-contiguous, swizzled)
    auto stage = [&](int slot, int tt) {
        short* dst = xs + slot * PLANE_SHORTS;
        const bool zero = ((unsigned)tt >= (unsigned)TD);   // SAME pad in t
#pragma unroll
        for (int i = 0; i < 13; ++i) {
            int idx = tid + i * 256;
            if (idx < PLANE_SHORTS) {
                unsigned u  = (unsigned)idx;
                int wp   = u % LW;             // w fastest -> coalesced 34-runs
                int rest = u / LW;
                int ic   = rest & 15;
                int hp   = rest >> 4;
                float v = 0.f;
                if (!zero) {
                    int hh = h0 + hp - 1;
                    int ww = w0 + wp - 1;
                    if ((unsigned)hh < 128u && (unsigned)ww < 128u)
                        v = xin[((size_t)ic * TD + tt) * HW + hh * 128 + ww];
                }
                int chunk = (ic >> 3) ^ ((wp >> 2) & 1);   // bank swizzle
                dst[(hp * LW + wp) * 16 + chunk * 8 + (ic & 7)] = f2bf(v);
            }
        }
    };

    stage(0, -1);    // tt=-1: zero plane (slot(tt) = (tt+1)%3)
    stage(1, 0);

    for (int t = 0; t < TD; ++t) {
        stage((t + 2) % 3, t + 1);          // tt=t+1 (zeros when 31)
        __syncthreads();

        float4v acc[2][3];
#pragma unroll
        for (int g = 0; g < 3; ++g) {
            float4v bv = (float4v){bval[g][0], bval[g][1], bval[g][2], bval[g][3]};
            acc[0][g] = bv;
            acc[1][g] = bv;
        }

        const int t3 = t % 3;
#pragma unroll
        for (int s = 0; s < 14; ++s) {
            int T = 2 * s + (q >> 1);       // this quad's tap
            if (T > 26) T = 26;             // pad tap: A==0, B is don't-care (finite)
            int kd = T / 9;
            int rr = T - kd * 9;
            int kh = rr / 3;
            int kw = rr - kh * 3;
            int slot = t3 + kd; slot = (slot >= 3) ? slot - 3 : slot;  // plane tt=t+kd-1
            int wp    = px + kw;
            int chunk = (q & 1) ^ ((wp >> 2) & 1);
            int idx8  = slot * PLANE8 + ((wv + kh) * LW + wp) * 2 + chunk;
            short8 b0 = xs8[idx8];          // ds_read_b128, tile 0
            short8 b1 = xs8[idx8 + 32];     // +16 w positions, same chunk parity
#pragma unroll
            for (int g = 0; g < 3; ++g) {
                acc[0][g] = __builtin_amdgcn_mfma_f32_16x16x32_bf16(afr[g][s], b0, acc[0][g], 0, 0, 0);
                acc[1][g] = __builtin_amdgcn_mfma_f32_16x16x32_bf16(afr[g][s], b1, acc[1][g], 0, 0, 0);
            }
        }

        // activations + fo-pool + store (all per-lane; ch = q*4+r, px aligned across gates)
#pragma unroll
        for (int tile = 0; tile < 2; ++tile) {
#pragma unroll
            for (int r = 0; r < 4; ++r) {
                float az = acc[tile][0][r];
                float af = acc[tile][1][r];
                float ao = acc[tile][2][r];
                float z = 1.f - 2.f / (__expf(2.f * az) + 1.f);   // tanh
                float f = 1.f / (1.f + __expf(-af));              // sigmoid
                float o = 1.f / (1.f + __expf(-ao));
                float c = f * cst[tile][r] + (1.f - f) * z;
                cst[tile][r] = c;
                po[(size_t)r * (TD * HW) + tile * 16] = o * c;
            }
        }
        po += HW;
        __syncthreads();    // protect ring slot overwritten by next stage()
    }
}

extern "C" void kernel_launch(void* const* d_in, const int* in_sizes, int n_in,
                              void* d_out, int out_size, void* d_ws, size_t ws_size,
                              hipStream_t stream) {
    const float* x    = (const float*)d_in[0];
    const float* wt   = (const float*)d_in[1];
    const float* bias = (const float*)d_in[2];
    float* out = (float*)d_out;

    // grid: n(4) x hblk(32) x wblk(4) = 512 blocks of 256 threads (4 waves)
    qrnn_mfma_kernel<<<dim3(512), dim3(256), 0, stream>>>(x, wt, bias, out);
}

// Round 3
// 306.450 us; speedup vs baseline: 10.1909x; 2.3690x over previous
//
#include <hip/hip_runtime.h>

// QRNN3D fused: conv3d(16->48,3x3x3,SAME) + gates + fo-pool via bf16 MFMA.
// Round 3: weights in LDS (round-2 spilled 168 VGPRs of A-frags -> scratch
// thrash: WRITE +93MB, FETCH +340MB). Conflict-free b128 LDS layouts, and
// staging global loads issued at top of iter t so the barrier vmcnt-drain
// lands after the MFMA block.
//
// GEMM: gates[48][px] = W[48][K=448] * im2col[K][px]; K = tap*16+ic,
// tap = kd*9+kh*3+kw (27 real, pad tap 27 has W==0).
// mfma_f32_16x16x32_bf16: A[m][k=q*8+j] = W, B[k][n=px], C/D col=lane&15,
// row=q*4+reg. Wave owns 32 px x 16 hidden ch; z/f/o accs lane-aligned so
// the t-recurrence is per-lane register math.

typedef __attribute__((ext_vector_type(8))) short short8;
typedef __attribute__((ext_vector_type(4))) float float4v;

#define TD 31
#define HW (128 * 128)
#define LH 6                         // 4 tile rows + 2 halo
#define LW 34                        // 32 tile cols + 2 halo
#define UNITS (LH * 2 * LW)          // 408 short8 units per plane: [hp][chunk][wp]
#define NSLOT 3
#define WUNITS (14 * 3 * 64)         // weight LDS: [s][g][lane] -> short8

__device__ __forceinline__ short f2bf(float f) {
    unsigned u = __float_as_uint(f);
    u = (u + 0x7FFFu + ((u >> 16) & 1u)) >> 16;   // RNE
    return (short)u;
}

__global__ __launch_bounds__(256, 2) void qrnn_mfma2(
    const float* __restrict__ x,     // (4,16,31,128,128)
    const float* __restrict__ wt,    // (48,16,27)
    const float* __restrict__ bias,  // (48)
    float* __restrict__ out)         // (4,16,31,128,128)
{
    __shared__ short8 wlds[WUNITS];          // 43008 B
    __shared__ short8 ring[NSLOT * UNITS];   // 19584 B  (total 62592 < 64K)

    const int tid  = threadIdx.x;
    const int lane = tid & 63;
    const int wv   = tid >> 6;       // wave id = h row in tile
    const int q    = lane >> 4;
    const int px   = lane & 15;
    const int b    = blockIdx.x;     // 512 blocks
    const int n    = b >> 7;
    const int h0   = ((b >> 2) & 31) * 4;
    const int w0   = (b & 3) * 32;

    const float* xin = x + (size_t)n * (16 * TD * HW);

    // ---- fill weight LDS once: wlds[(s*3+g)*64 + lane] = A-frag ----
    for (int k = 0; k < 11; ++k) {
        int u = tid + k * 256;
        if (u < WUNITS) {
            int l = u & 63, rest = u >> 6;
            int g = rest % 3, s = rest / 3;
            int qq = l >> 4, m = l & 15;
            short8 a;
#pragma unroll
            for (int j = 0; j < 8; ++j) {
                int kk = s * 32 + qq * 8 + j;
                int tap = kk >> 4, ic = kk & 15;
                float v = (tap < 27) ? wt[((size_t)((g * 16 + m) * 16 + ic)) * 27 + tap] : 0.f;
                a[j] = f2bf(v);
            }
            wlds[u] = a;
        }
    }

    // ---- staging coords (t-invariant): unit u -> (hp, chunk, wp) ----
    float rv[2][8];
    int s_hp[2], s_wp[2], s_ck[2]; bool s_in[2];
#pragma unroll
    for (int i = 0; i < 2; ++i) {
        int u  = tid + i * 256;
        int uu = (u < UNITS) ? u : 0;
        s_wp[i] = uu % LW;
        int rest = uu / LW;
        s_ck[i] = rest & 1;
        s_hp[i] = rest >> 1;
        s_in[i] = (u < UNITS);
    }

    auto issue_loads = [&](int tt) {       // plane tt -> rv (8 coalesced rows/unit)
        const bool tz = ((unsigned)tt >= 31u);
        const int tc = tz ? 0 : tt;
#pragma unroll
        for (int i = 0; i < 2; ++i) {
            int hh = h0 + s_hp[i] - 1;
            int ww = w0 + s_wp[i] - 1;
            bool ok = s_in[i] && !tz && ((unsigned)hh < 128u) && ((unsigned)ww < 128u);
            const float* src = xin + ((size_t)(s_ck[i] * 8) * TD + tc) * HW + hh * 128 + ww;
#pragma unroll
            for (int j = 0; j < 8; ++j)
                rv[i][j] = ok ? src[(size_t)j * TD * HW] : 0.f;
        }
    };
    auto write_lds = [&](int slot) {       // rv -> ring[slot], b128 conflict-free
#pragma unroll
        for (int i = 0; i < 2; ++i) {
            if (s_in[i]) {
                short8 v;
#pragma unroll
                for (int j = 0; j < 8; ++j) v[j] = f2bf(rv[i][j]);
                ring[slot * UNITS + tid + i * 256] = v;
            }
        }
    };

    // bias per lane: channel = g*16 + q*4 + r
    float bval[3][4];
#pragma unroll
    for (int g = 0; g < 3; ++g)
#pragma unroll
        for (int r = 0; r < 4; ++r)
            bval[g][r] = bias[g * 16 + q * 4 + r];

    float* po = out + ((size_t)(n * 16 + q * 4) * TD) * HW
                    + (size_t)(h0 + wv) * 128 + w0 + px;
    float cst[2][4] = {{0.f,0.f,0.f,0.f},{0.f,0.f,0.f,0.f}};

    // ---- prologue: planes -1,0,1 into slots 0,1,2 (slot(tt) = (tt+1)%3) ----
    issue_loads(-1); write_lds(0);
    issue_loads(0);  write_lds(1);
    issue_loads(1);  write_lds(2);
    __syncthreads();

    for (int t = 0; t < TD; ++t) {
        const int t3 = t % 3;
        issue_loads(t + 2);              // in flight across the MFMA block

        float4v acc[2][3];
#pragma unroll
        for (int g = 0; g < 3; ++g) {
            float4v bv = (float4v){bval[g][0], bval[g][1], bval[g][2], bval[g][3]};
            acc[0][g] = bv; acc[1][g] = bv;
        }

#pragma unroll
        for (int s = 0; s < 14; ++s) {
            int T = 2 * s + (q >> 1); if (T > 26) T = 26;  // pad tap: W==0
            int kd = T / 9, rr = T - kd * 9, kh = rr / 3, kw = rr - kh * 3;
            int slot = t3 + kd; if (slot >= NSLOT) slot -= NSLOT;   // plane t+kd-1
            int base = slot * UNITS + ((wv + kh) * 2 + (q & 1)) * LW + px + kw;
            short8 b0 = ring[base];          // ds_read_b128, conflict-free
            short8 b1 = ring[base + 16];     // +16 w, same chunk row
#pragma unroll
            for (int g = 0; g < 3; ++g) {
                short8 wf = wlds[(s * 3 + g) * 64 + lane];
                acc[0][g] = __builtin_amdgcn_mfma_f32_16x16x32_bf16(wf, b0, acc[0][g], 0, 0, 0);
                acc[1][g] = __builtin_amdgcn_mfma_f32_16x16x32_bf16(wf, b1, acc[1][g], 0, 0, 0);
            }
        }
        __syncthreads();                 // reads of slot t%3 done; vmcnt drains here
        write_lds(t3);                   // plane t+2 -> slot t%3

        // activations + fo-pool + store
#pragma unroll
        for (int tile = 0; tile < 2; ++tile) {
#pragma unroll
            for (int r = 0; r < 4; ++r) {
                float az = acc[tile][0][r];
                float af = acc[tile][1][r];
                float ao = acc[tile][2][r];
                float z = 1.f - 2.f / (__expf(2.f * az) + 1.f);
                float f = 1.f / (1.f + __expf(-af));
                float o = 1.f / (1.f + __expf(-ao));
                float c = f * cst[tile][r] + (1.f - f) * z;
                cst[tile][r] = c;
                po[(size_t)r * (TD * HW) + tile * 16] = o * c;
            }
        }
        po += HW;
        __syncthreads();                 // ds_writes visible before next iter
    }
}

extern "C" void kernel_launch(void* const* d_in, const int* in_sizes, int n_in,
                              void* d_out, int out_size, void* d_ws, size_t ws_size,
                              hipStream_t stream) {
    const float* x    = (const float*)d_in[0];
    const float* wt   = (const float*)d_in[1];
    const float* bias = (const float*)d_in[2];
    float* out = (float*)d_out;

    // grid: n(4) x hblk(32) x wblk(4) = 512 blocks of 256 threads (4 waves)
    qrnn_mfma2<<<dim3(512), dim3(256), 0, stream>>>(x, wt, bias, out);
}